// Round 4
// baseline (411.967 us; speedup 1.0000x reference)
//
#include <hip/hip_runtime.h>

// LSTM, barrier-free per-wave MFMA formulation. Round 11: 2-group software
// pipeline. B=4096, T=512, I=10, H=32, O=1. Gates i,f,g,o.
//
// R10 counters: MfmaUtil 20%, VALUBusy 38%, dur flat at ~281us -> 42% of the
// window is dependency stall: with 1 wave/SIMD and all 4 batches inside the
// SAME MFMA calls, the per-step ring (MFMA drain ~310cyc -> activation chain
// ~300cyc -> fp16 pack + LDS write->read ~240cyc) is fully serial.
//
// R11: the wave's 4 batches split into two independent groups (X = batches
// 0,1; Y = batches 2,3), each in the proven R9 dup-8 mapping (A rows 0-7 =
// 1st batch, 8-15 = 2nd; 16 MFMAs/group/step; act 1 cell/lane/group).
// Groups share B-frags (same weights). Per-step source order:
//   fragX -> MFMA_X -> fragY -> MFMA_Y -> act_X -> write_X -> act_Y -> write_Y
// so act_X overlaps MFMA_Y's pipe occupancy and X's LDS round-trip hides
// under act_Y. Act work/lane unchanged vs R10 (2 cells); MFMA 32/step/wave.
//
// K-packing per group unchanged (R9 merged-K, 64/64 slots/tile):
//   MFMA 1: A = h_hi (k0..31),                B = W_hh
//   MFMA 2: A = {x_hat k0..9 | h_lo k10..31}, B = {W_ih | W_hh 10..31}
// fp16 2-term h split; lo-correction dropped on channels 0..9 (absmax 2e-3,
// verified R9/R10). Biases folded into the sigmoid fma.
//
// Act mapping per group (R9, verified): lane (Q=lane>>4, L=lane&15) handles
// group-batch Q>>1, hid L+16*(Q&1); gates via qh=Q&1 selects from v[0..7].
// A-side group-batch = L>>3.
//
// h round-trips through a private per-wave LDS buffer (wave-ordered DS =>
// NO barriers). hbuf[2][2][4][32] fp16 = 1 KiB; batches 0,1 = X; 2,3 = Y.
//
// Grid: 1024 blocks x 64 threads (1 wave/block), 4 batches/wave,
// launch_bounds(64,1).

#define T_SZ 512
#define I_SZ 10
#define H_SZ 32

typedef _Float16 half8  __attribute__((ext_vector_type(8)));
typedef __fp16   fp16x2 __attribute__((ext_vector_type(2)));
typedef float    f32x4  __attribute__((ext_vector_type(4)));
typedef int      i32x4  __attribute__((ext_vector_type(4)));

union FH { i32x4 i; half8 h; };
static __device__ __forceinline__ half8 fragv(i32x4 v) { FH u; u.i = v; return u.h; }
static __device__ __forceinline__ half8 frag4(int a, int b, int c, int d) {
    FH u; u.i = (i32x4){a, b, c, d}; return u.h;
}

// pack 2 fp32 -> 2 fp16 in one dword (v_cvt_pkrtz_f16_f32): low = lo, high = hi
static __device__ __forceinline__ int pk16(float lo, float hi) {
    union { fp16x2 h; int i; } u;
    u.h = __builtin_amdgcn_cvt_pkrtz(lo, hi);
    return u.i;
}

#define MFMAH(A, B, C) __builtin_amdgcn_mfma_f32_16x16x32_f16((A), (B), (C), 0, 0, 0)

__global__ __launch_bounds__(64, 1)
void lstm_wave(const float* __restrict__ x, const float* __restrict__ W_ih,
               const float* __restrict__ W_hh, const float* __restrict__ b_ih,
               const float* __restrict__ b_hh, const float* __restrict__ W_dense,
               const float* __restrict__ b_dense, float* __restrict__ out)
{
    const int lane  = threadIdx.x;        // 0..63 (block = one wave)
    const int L     = lane & 15;          // A m-row / C col
    const int Q     = lane >> 4;          // k-quad
    const int bbase = blockIdx.x * 4;     // 1024 blocks x 4 batches

    const int bAg  = L >> 3;              // A-side batch within group (dup-8)
    const int bAct = Q >> 1;              // act-side batch within group
    const int hidA = L + 16 * (Q & 1);    // act-side hidden index

    // ---- B-fragments for all 8 tiles (one-time, shared by both groups) ----
    // tile tau = 2*gate + hhalf: W row = 32*gate + 16*hhalf + L
    int bhh[8][4];
    int bm[8][4];
    #pragma unroll
    for (int tau = 0; tau < 8; ++tau) {
        const int wr = 32 * (tau >> 1) + 16 * (tau & 1) + L;
        const float* ph = W_hh + wr * H_SZ + 8 * Q;
        #pragma unroll
        for (int d = 0; d < 4; ++d) {
            float2 v = *(const float2*)(ph + 2 * d);
            bhh[tau][d] = pk16(v.x, v.y);
        }
        if (Q == 0) {
            const float* pi = W_ih + wr * I_SZ;       // k0..7 = W_ih cols 0..7
            #pragma unroll
            for (int d = 0; d < 4; ++d) {
                float2 v = *(const float2*)(pi + 2 * d);
                bm[tau][d] = pk16(v.x, v.y);
            }
        } else if (Q == 1) {
            // k8,9 = W_ih cols 8,9; k10..15 = W_hh cols 10..15
            float2 v = *(const float2*)(W_ih + wr * I_SZ + 8);
            bm[tau][0] = pk16(v.x, v.y);
            #pragma unroll
            for (int d = 1; d < 4; ++d) {
                float2 w = *(const float2*)(W_hh + wr * H_SZ + 8 + 2 * d);
                bm[tau][d] = pk16(w.x, w.y);
            }
        } else {
            bm[tau][0] = bhh[tau][0]; bm[tau][1] = bhh[tau][1];
            bm[tau][2] = bhh[tau][2]; bm[tau][3] = bhh[tau][3];
        }
    }

    // ---- biases folded into sigmoid fma (same hid for both groups) ----
    const float nL = -1.4426950f;     // -log2(e)       (sigmoid)
    const float m2 = -2.8853901f;     // -2*log2(e)     (tanh via 2*sig(2x)-1)
    const float mbi = nL * (b_ih[hidA]      + b_hh[hidA]);
    const float mbf = nL * (b_ih[32 + hidA] + b_hh[32 + hidA]);
    const float mbg = m2 * (b_ih[64 + hidA] + b_hh[64 + hidA]);
    const float mbo = nL * (b_ih[96 + hidA] + b_hh[96 + hidA]);

    // ---- per-wave LDS h buffer: [buf][plane hi/lo][batch 0..3][hid] fp16 ----
    // batches 0,1 = group X; batches 2,3 = group Y
    __shared__ __attribute__((aligned(16))) _Float16 hbuf[2][2][4][H_SZ];  // 1 KiB
    {
        int* zz = (int*)&hbuf[0][0][0][0];
        zz[lane] = 0; zz[lane + 64] = 0; zz[lane + 128] = 0; zz[lane + 192] = 0;
    }
    // wave-ordered DS: zeros visible to this wave's later reads, no barrier.

    // ---- x streams: 2-deep prefetch per group ----
    const float* xrowX = x + (size_t)(bbase + bAg)     * (T_SZ * I_SZ);
    const float* xrowY = x + (size_t)(bbase + 2 + bAg) * (T_SZ * I_SZ);
    float2 xA0 = *(const float2*)(xrowX + 0), xA1 = *(const float2*)(xrowX + 2),
           xA2 = *(const float2*)(xrowX + 4), xA3 = *(const float2*)(xrowX + 6),
           xA4 = *(const float2*)(xrowX + 8);
    float2 xB0 = *(const float2*)(xrowX + I_SZ + 0), xB1 = *(const float2*)(xrowX + I_SZ + 2),
           xB2 = *(const float2*)(xrowX + I_SZ + 4), xB3 = *(const float2*)(xrowX + I_SZ + 6),
           xB4 = *(const float2*)(xrowX + I_SZ + 8);
    float2 yA0 = *(const float2*)(xrowY + 0), yA1 = *(const float2*)(xrowY + 2),
           yA2 = *(const float2*)(xrowY + 4), yA3 = *(const float2*)(xrowY + 6),
           yA4 = *(const float2*)(xrowY + 8);
    float2 yB0 = *(const float2*)(xrowY + I_SZ + 0), yB1 = *(const float2*)(xrowY + I_SZ + 2),
           yB2 = *(const float2*)(xrowY + I_SZ + 4), yB3 = *(const float2*)(xrowY + I_SZ + 6),
           yB4 = *(const float2*)(xrowY + I_SZ + 8);

    const f32x4 zerov = {0.f, 0.f, 0.f, 0.f};
    float cstX = 0.0f, cstY = 0.0f;
    float hXlast = 0.0f, hYlast = 0.0f;
    const bool q0 = (Q == 0), q1 = (Q == 1);
    const bool qh = (Q & 1);

    for (int t = 0; t < T_SZ; t += 2) {
        #pragma unroll
        for (int u = 0; u < 2; ++u) {
            const int rb = u, wb = u ^ 1;

            // ---- group X: frags + 16 MFMAs ----
            i32x4 hhiX_ = *(const i32x4*)&hbuf[rb][0][bAg][8 * Q];
            i32x4 loX_  = *(const i32x4*)&hbuf[rb][1][bAg][8 * Q];
            float2 u0 = u ? xB0 : xA0, u1 = u ? xB1 : xA1, u2 = u ? xB2 : xA2,
                   u3 = u ? xB3 : xA3, u4 = u ? xB4 : xA4;
            int pX0 = pk16(u0.x, u0.y), pX1 = pk16(u1.x, u1.y), pX2 = pk16(u2.x, u2.y),
                pX3 = pk16(u3.x, u3.y), pX4 = pk16(u4.x, u4.y);
            half8 mfX = fragv((i32x4){ q0 ? pX0 : (q1 ? pX4 : loX_[0]),
                                       q0 ? pX1 : loX_[1],
                                       q0 ? pX2 : loX_[2],
                                       q0 ? pX3 : loX_[3] });
            half8 hhiX = fragv(hhiX_);
            float vX[8];
            #pragma unroll
            for (int tau = 0; tau < 8; ++tau) {
                f32x4 acc = MFMAH(mfX, frag4(bm[tau][0], bm[tau][1], bm[tau][2], bm[tau][3]), zerov);
                acc = MFMAH(hhiX, frag4(bhh[tau][0], bhh[tau][1], bhh[tau][2], bhh[tau][3]), acc);
                vX[tau] = acc[0];
            }

            // ---- group Y: frags + 16 MFMAs (issues while act_X waits) ----
            i32x4 hhiY_ = *(const i32x4*)&hbuf[rb][0][2 + bAg][8 * Q];
            i32x4 loY_  = *(const i32x4*)&hbuf[rb][1][2 + bAg][8 * Q];
            float2 w0 = u ? yB0 : yA0, w1 = u ? yB1 : yA1, w2 = u ? yB2 : yA2,
                   w3 = u ? yB3 : yA3, w4 = u ? yB4 : yA4;
            int pY0 = pk16(w0.x, w0.y), pY1 = pk16(w1.x, w1.y), pY2 = pk16(w2.x, w2.y),
                pY3 = pk16(w3.x, w3.y), pY4 = pk16(w4.x, w4.y);
            half8 mfY = fragv((i32x4){ q0 ? pY0 : (q1 ? pY4 : loY_[0]),
                                       q0 ? pY1 : loY_[1],
                                       q0 ? pY2 : loY_[2],
                                       q0 ? pY3 : loY_[3] });
            half8 hhiY = fragv(hhiY_);
            float vY[8];
            #pragma unroll
            for (int tau = 0; tau < 8; ++tau) {
                f32x4 acc = MFMAH(mfY, frag4(bm[tau][0], bm[tau][1], bm[tau][2], bm[tau][3]), zerov);
                acc = MFMAH(hhiY, frag4(bhh[tau][0], bhh[tau][1], bhh[tau][2], bhh[tau][3]), acc);
                vY[tau] = acc[0];
            }

            // refill consumed x sets from t+2+u (distance-2 prefetch)
            if (t + 2 + u < T_SZ) {
                const float* xrX = xrowX + (t + 2 + u) * I_SZ;
                const float* xrY = xrowY + (t + 2 + u) * I_SZ;
                if (u == 0) {
                    xA0 = *(const float2*)(xrX + 0); xA1 = *(const float2*)(xrX + 2);
                    xA2 = *(const float2*)(xrX + 4); xA3 = *(const float2*)(xrX + 6);
                    xA4 = *(const float2*)(xrX + 8);
                    yA0 = *(const float2*)(xrY + 0); yA1 = *(const float2*)(xrY + 2);
                    yA2 = *(const float2*)(xrY + 4); yA3 = *(const float2*)(xrY + 6);
                    yA4 = *(const float2*)(xrY + 8);
                } else {
                    xB0 = *(const float2*)(xrX + 0); xB1 = *(const float2*)(xrX + 2);
                    xB2 = *(const float2*)(xrX + 4); xB3 = *(const float2*)(xrX + 6);
                    xB4 = *(const float2*)(xrX + 8);
                    yB0 = *(const float2*)(xrY + 0); yB1 = *(const float2*)(xrY + 2);
                    yB2 = *(const float2*)(xrY + 4); yB3 = *(const float2*)(xrY + 6);
                    yB4 = *(const float2*)(xrY + 8);
                }
            }

            // ---- act X (overlaps MFMA_Y pipe) ----
            {
                float vi = qh ? vX[1] : vX[0];
                float vf = qh ? vX[3] : vX[2];
                float vg = qh ? vX[5] : vX[4];
                float vo = qh ? vX[7] : vX[6];
                float ig = __builtin_amdgcn_rcpf(1.0f + __builtin_amdgcn_exp2f(fmaf(nL, vi, mbi)));
                float fg = __builtin_amdgcn_rcpf(1.0f + __builtin_amdgcn_exp2f(fmaf(nL, vf, mbf)));
                float gr = __builtin_amdgcn_rcpf(1.0f + __builtin_amdgcn_exp2f(fmaf(m2, vg, mbg)));
                float gg = fmaf(2.0f, gr, -1.0f);
                float og = __builtin_amdgcn_rcpf(1.0f + __builtin_amdgcn_exp2f(fmaf(nL, vo, mbo)));
                cstX = fmaf(fg, cstX, ig * gg);
                float tr = __builtin_amdgcn_rcpf(1.0f + __builtin_amdgcn_exp2f(m2 * cstX));
                float th = fmaf(2.0f, tr, -1.0f);
                float h  = og * th;
                hXlast = h;
                _Float16 hh = (_Float16)h;
                _Float16 hl = (_Float16)(h - (float)hh);
                hbuf[wb][0][bAct][hidA] = hh;
                hbuf[wb][1][bAct][hidA] = hl;
            }

            // ---- act Y (X's LDS writes complete underneath) ----
            {
                float vi = qh ? vY[1] : vY[0];
                float vf = qh ? vY[3] : vY[2];
                float vg = qh ? vY[5] : vY[4];
                float vo = qh ? vY[7] : vY[6];
                float ig = __builtin_amdgcn_rcpf(1.0f + __builtin_amdgcn_exp2f(fmaf(nL, vi, mbi)));
                float fg = __builtin_amdgcn_rcpf(1.0f + __builtin_amdgcn_exp2f(fmaf(nL, vf, mbf)));
                float gr = __builtin_amdgcn_rcpf(1.0f + __builtin_amdgcn_exp2f(fmaf(m2, vg, mbg)));
                float gg = fmaf(2.0f, gr, -1.0f);
                float og = __builtin_amdgcn_rcpf(1.0f + __builtin_amdgcn_exp2f(fmaf(nL, vo, mbo)));
                cstY = fmaf(fg, cstY, ig * gg);
                float tr = __builtin_amdgcn_rcpf(1.0f + __builtin_amdgcn_exp2f(m2 * cstY));
                float th = fmaf(2.0f, tr, -1.0f);
                float h  = og * th;
                hYlast = h;
                _Float16 hh = (_Float16)h;
                _Float16 hl = (_Float16)(h - (float)hh);
                hbuf[wb][0][2 + bAct][hidA] = hh;
                hbuf[wb][1][2 + bAct][hidA] = hl;
            }
            // wave-ordered DS: next iteration's reads see these writes.
        }
    }

    // ---- dense head: out[b] = h . W_dense + b_dense ----
    // group X: batch bAct=0 in lanes 0-31, bAct=1 in lanes 32-63 (hids L+16(Q&1))
    float vx = hXlast * W_dense[hidA];
    float vy = hYlast * W_dense[hidA];
    #pragma unroll
    for (int m = 16; m >= 1; m >>= 1) {
        vx += __shfl_xor(vx, m);          // reduce within 32-lane halves
        vy += __shfl_xor(vy, m);
    }
    if (lane == 0)  { out[bbase + 0] = vx + b_dense[0]; out[bbase + 2] = vy + b_dense[0]; }
    if (lane == 32) { out[bbase + 1] = vx + b_dense[0]; out[bbase + 3] = vy + b_dense[0]; }
}

extern "C" void kernel_launch(void* const* d_in, const int* in_sizes, int n_in,
                              void* d_out, int out_size, void* d_ws, size_t ws_size,
                              hipStream_t stream) {
    const float* x       = (const float*)d_in[0];
    const float* W_ih    = (const float*)d_in[1];
    const float* W_hh    = (const float*)d_in[2];
    const float* b_ih    = (const float*)d_in[3];
    const float* b_hh    = (const float*)d_in[4];
    const float* W_dense = (const float*)d_in[5];
    const float* b_dense = (const float*)d_in[6];
    float* out = (float*)d_out;

    // 1024 blocks x 64 threads = 1024 independent waves (1/SIMD), 4 batches
    // each (2 pipelined groups of 2)
    lstm_wave<<<dim3(1024), dim3(64), 0, stream>>>(
        x, W_ih, W_hh, b_ih, b_hh, W_dense, b_dense, out);
}

// Round 7
// 316.955 us; speedup vs baseline: 1.2998x; 1.2998x over previous
//
#include <hip/hip_runtime.h>

// LSTM, barrier-free per-wave MFMA formulation. Round 13 (= R12 semantics,
// re-rolled gate loop; 2nd resubmit after infra failures).
// R10 dataflow + trans-reduction + gate-interleaved MFMA/act schedule.
// B=4096, T=512, I=10, H=32, O=1. Gates i,f,g,o.
//
// R10 budget @ ~2.3GHz: window 1250 cyc/step = MFMA pipe 264 + VALU ~500
// (of which ~320 = 20 quarter-rate transcendentals x 16 cyc) + ~400 stall
// (act strictly after all MFMAs + LDS ring). This round attacks both:
//  (a) shared-denominator gates: i*g = (1-B)/((1+A)(1+B)), f = 1/(1+F),
//      h = o*tanh(c) = (1-D)/((1+O)(1+D)) -> 5 exp2 + 3 rcp per cell
//      (was 5+5): 16 trans/step.
//  (b) gate-interleaved schedule: per gate, the tile-pair's MFMAs then that
//      gate's exp2 pair -> trans pipe crunches while matrix pipe is busy;
//      only the rcp/combine chains remain after the last MFMA.
//
// Mappings (all verified R3-R10):
//  A row m = lane L (batch = L>>2, dup-4); A[m][k=8Q+j]; B[k][n=L];
//  C col = L, row = 4Q+reg; reg 0 of quad Q = batch Q.
//  Act: lane (Q,L) owns batch Q, hids {L, L+16}; cell0 gates from even
//  tiles, cell1 from odd tiles.
// K-packing (R9 merged-K): per tile MFMA1 A={x_hat k0..9 | h_lo k10..31},
// MFMA2 A=h_hi k0..31. fp16 2-term h split, lo dropped on ch 0..9
// (absmax 2e-3 verified). Biases folded into exp2 args.
// h ring through private per-wave LDS (wave-ordered DS, no barriers).
//
// Grid: 1024 blocks x 64 threads (1 wave/block), 4 batches/wave,
// launch_bounds(64,1).

#define T_SZ 512
#define I_SZ 10
#define H_SZ 32

typedef _Float16 half8  __attribute__((ext_vector_type(8)));
typedef __fp16   fp16x2 __attribute__((ext_vector_type(2)));
typedef float    f32x4  __attribute__((ext_vector_type(4)));
typedef int      i32x4  __attribute__((ext_vector_type(4)));

union FH { i32x4 i; half8 h; };
static __device__ __forceinline__ half8 fragv(i32x4 v) { FH u; u.i = v; return u.h; }
static __device__ __forceinline__ half8 frag4(int a, int b, int c, int d) {
    FH u; u.i = (i32x4){a, b, c, d}; return u.h;
}

// pack 2 fp32 -> 2 fp16 in one dword (v_cvt_pkrtz_f16_f32)
static __device__ __forceinline__ int pk16(float lo, float hi) {
    union { fp16x2 h; int i; } u;
    u.h = __builtin_amdgcn_cvt_pkrtz(lo, hi);
    return u.i;
}

#define MFMAH(A, B, C) __builtin_amdgcn_mfma_f32_16x16x32_f16((A), (B), (C), 0, 0, 0)
#define EXP2(x) __builtin_amdgcn_exp2f(x)
#define RCP(x)  __builtin_amdgcn_rcpf(x)

__global__ __launch_bounds__(64, 1)
void lstm_wave(const float* __restrict__ x, const float* __restrict__ W_ih,
               const float* __restrict__ W_hh, const float* __restrict__ b_ih,
               const float* __restrict__ b_hh, const float* __restrict__ W_dense,
               const float* __restrict__ b_dense, float* __restrict__ out)
{
    const int lane  = threadIdx.x;        // 0..63 (block = one wave)
    const int L     = lane & 15;          // A m-row / C col
    const int Q     = lane >> 4;          // k-quad / C row-quad (= act batch)
    const int bbase = blockIdx.x * 4;     // 1024 blocks x 4 batches

    const int bA = L >> 2;                // A-side batch (4 dup rows per batch)
    const int h0 = L, h1 = L + 16;        // this lane's two hidden channels

    // ---- B-fragments for all 8 tiles (one-time) ----
    // tile tau = 2*gate + hhalf: W row = 32*gate + 16*hhalf + L
    int bhh[8][4];
    int bm[8][4];
    #pragma unroll
    for (int tau = 0; tau < 8; ++tau) {
        const int wr = 32 * (tau >> 1) + 16 * (tau & 1) + L;
        const float* ph = W_hh + wr * H_SZ + 8 * Q;
        #pragma unroll
        for (int d = 0; d < 4; ++d) {
            float2 v = *(const float2*)(ph + 2 * d);
            bhh[tau][d] = pk16(v.x, v.y);
        }
        if (Q == 0) {
            const float* pi = W_ih + wr * I_SZ;       // k0..7 = W_ih cols 0..7
            #pragma unroll
            for (int d = 0; d < 4; ++d) {
                float2 v = *(const float2*)(pi + 2 * d);
                bm[tau][d] = pk16(v.x, v.y);
            }
        } else if (Q == 1) {
            // k8,9 = W_ih cols 8,9; k10..15 = W_hh cols 10..15
            float2 v = *(const float2*)(W_ih + wr * I_SZ + 8);
            bm[tau][0] = pk16(v.x, v.y);
            #pragma unroll
            for (int d = 1; d < 4; ++d) {
                float2 w = *(const float2*)(W_hh + wr * H_SZ + 8 + 2 * d);
                bm[tau][d] = pk16(w.x, w.y);
            }
        } else {
            bm[tau][0] = bhh[tau][0]; bm[tau][1] = bhh[tau][1];
            bm[tau][2] = bhh[tau][2]; bm[tau][3] = bhh[tau][3];
        }
    }

    // ---- biases folded into exp2 args; per gate, both cells ----
    const float nL = -1.4426950f;     // -log2(e)       (sigmoid)
    const float m2 = -2.8853901f;     // -2*log2(e)     (tanh via (1-D)/(1+D))
    float mb0[4], mb1[4];             // gate order i,f,g,o
    #pragma unroll
    for (int gt = 0; gt < 4; ++gt) {
        const float sc = (gt == 2) ? m2 : nL;
        mb0[gt] = sc * (b_ih[32 * gt + h0] + b_hh[32 * gt + h0]);
        mb1[gt] = sc * (b_ih[32 * gt + h1] + b_hh[32 * gt + h1]);
    }

    // ---- per-wave LDS h buffer: [buf][plane hi/lo][batch 0..3][hid] fp16 ----
    __shared__ __attribute__((aligned(16))) _Float16 hbuf[2][2][4][H_SZ];  // 1 KiB
    {
        int* zz = (int*)&hbuf[0][0][0][0];
        zz[lane] = 0; zz[lane + 64] = 0; zz[lane + 128] = 0; zz[lane + 192] = 0;
    }
    // wave-ordered DS: zeros visible to this wave's later reads, no barrier.

    // ---- x stream: 2-deep prefetch (each lane loads its A-side batch row) ----
    const float* xrow = x + (size_t)(bbase + bA) * (T_SZ * I_SZ);
    float2 xa0 = *(const float2*)(xrow + 0), xa1 = *(const float2*)(xrow + 2),
           xa2 = *(const float2*)(xrow + 4), xa3 = *(const float2*)(xrow + 6),
           xa4 = *(const float2*)(xrow + 8);
    float2 xb0 = *(const float2*)(xrow + I_SZ + 0), xb1 = *(const float2*)(xrow + I_SZ + 2),
           xb2 = *(const float2*)(xrow + I_SZ + 4), xb3 = *(const float2*)(xrow + I_SZ + 6),
           xb4 = *(const float2*)(xrow + I_SZ + 8);

    const f32x4 zerov = {0.f, 0.f, 0.f, 0.f};
    float cst0 = 0.0f, cst1 = 0.0f;
    float h0last = 0.0f, h1last = 0.0f;
    const bool q0 = (Q == 0), q1 = (Q == 1);

    for (int t = 0; t < T_SZ; t += 2) {
        #pragma unroll
        for (int u = 0; u < 2; ++u) {
            const int rb = u, wb = u ^ 1;

            // h fragments from private LDS (A-frag order, broadcast reads)
            i32x4 hhi_ = *(const i32x4*)&hbuf[rb][0][bA][8 * Q];
            i32x4 lo_  = *(const i32x4*)&hbuf[rb][1][bA][8 * Q];

            // x_hat packs (u is compile-time; selects fold away)
            float2 y0 = u ? xb0 : xa0, y1 = u ? xb1 : xa1, y2 = u ? xb2 : xa2,
                   y3 = u ? xb3 : xa3, y4 = u ? xb4 : xa4;
            int p0 = pk16(y0.x, y0.y), p1 = pk16(y1.x, y1.y), p2 = pk16(y2.x, y2.y),
                p3 = pk16(y3.x, y3.y), p4 = pk16(y4.x, y4.y);

            // merged A-frag: k0..9 = x_hat, k10..31 = h_lo channels 10..31
            half8 mf = fragv((i32x4){ q0 ? p0 : (q1 ? p4 : lo_[0]),
                                      q0 ? p1 : lo_[1],
                                      q0 ? p2 : lo_[2],
                                      q0 ? p3 : lo_[3] });
            half8 hhi = fragv(hhi_);

            // ---- gate loop: MFMA tile-pair, then that gate's exp2 pair ----
            // e0/e1 gate order i,f,g,o; cell0 from even tile, cell1 from odd
            float e0[4], e1[4];
            #pragma unroll
            for (int gt = 0; gt < 4; ++gt) {
                const float sc = (gt == 2) ? m2 : nL;
                const int te = 2 * gt, to = 2 * gt + 1;
                f32x4 ae = MFMAH(mf,  frag4(bm[te][0],  bm[te][1],  bm[te][2],  bm[te][3]),  zerov);
                ae       = MFMAH(hhi, frag4(bhh[te][0], bhh[te][1], bhh[te][2], bhh[te][3]), ae);
                f32x4 ao = MFMAH(mf,  frag4(bm[to][0],  bm[to][1],  bm[to][2],  bm[to][3]),  zerov);
                ao       = MFMAH(hhi, frag4(bhh[to][0], bhh[to][1], bhh[to][2], bhh[to][3]), ao);
                e0[gt] = EXP2(fmaf(sc, ae[0], mb0[gt]));
                e1[gt] = EXP2(fmaf(sc, ao[0], mb1[gt]));
            }

            // refill consumed x set from t+2+u (loads fly under the combines)
            if (t + 2 + u < T_SZ) {
                const float* xr = xrow + (t + 2 + u) * I_SZ;
                if (u == 0) {
                    xa0 = *(const float2*)(xr + 0); xa1 = *(const float2*)(xr + 2);
                    xa2 = *(const float2*)(xr + 4); xa3 = *(const float2*)(xr + 6);
                    xa4 = *(const float2*)(xr + 8);
                } else {
                    xb0 = *(const float2*)(xr + 0); xb1 = *(const float2*)(xr + 2);
                    xb2 = *(const float2*)(xr + 4); xb3 = *(const float2*)(xr + 6);
                    xb4 = *(const float2*)(xr + 8);
                }
            }

            // ---- combine chains (shared-denominator gates, 3 rcp/cell) ----
            // i*g~ = (1-B)/((1+A)(1+B)); f = 1/(1+F); h = (1-D)/((1+O)(1+D))
            {
                float eA = e0[0], eF = e0[1], eG = e0[2], eO = e0[3];
                float fg  = RCP(1.0f + eF);
                float igg = (1.0f - eG) * RCP((1.0f + eA) * (1.0f + eG));
                cst0 = fmaf(fg, cst0, igg);
                float eD = EXP2(m2 * cst0);
                h0last = (1.0f - eD) * RCP((1.0f + eO) * (1.0f + eD));
            }
            {
                float eA = e1[0], eF = e1[1], eG = e1[2], eO = e1[3];
                float fg  = RCP(1.0f + eF);
                float igg = (1.0f - eG) * RCP((1.0f + eA) * (1.0f + eG));
                cst1 = fmaf(fg, cst1, igg);
                float eD = EXP2(m2 * cst1);
                h1last = (1.0f - eD) * RCP((1.0f + eO) * (1.0f + eD));
            }

            // h write-back, fp16 2-term split, [plane][batch][hid] layout
            _Float16 a0h = (_Float16)h0last;
            _Float16 a0l = (_Float16)(h0last - (float)a0h);
            _Float16 a1h = (_Float16)h1last;
            _Float16 a1l = (_Float16)(h1last - (float)a1h);
            hbuf[wb][0][Q][h0] = a0h;
            hbuf[wb][0][Q][h1] = a1h;
            hbuf[wb][1][Q][h0] = a0l;
            hbuf[wb][1][Q][h1] = a1l;
            // wave-ordered DS: next iteration's reads see these writes.
        }
    }

    // ---- dense head: out[b] = h . W_dense + b_dense ----
    // lane (Q,L) holds hids {L, L+16} of batch Q; reduce over the 16-lane quad
    float v = h0last * W_dense[h0] + h1last * W_dense[h1];
    #pragma unroll
    for (int m = 8; m >= 1; m >>= 1)
        v += __shfl_xor(v, m);            // reduce within each 16-lane quad
    if (L == 0) out[bbase + Q] = v + b_dense[0];
}

extern "C" void kernel_launch(void* const* d_in, const int* in_sizes, int n_in,
                              void* d_out, int out_size, void* d_ws, size_t ws_size,
                              hipStream_t stream) {
    const float* x       = (const float*)d_in[0];
    const float* W_ih    = (const float*)d_in[1];
    const float* W_hh    = (const float*)d_in[2];
    const float* b_ih    = (const float*)d_in[3];
    const float* b_hh    = (const float*)d_in[4];
    const float* W_dense = (const float*)d_in[5];
    const float* b_dense = (const float*)d_in[6];
    float* out = (float*)d_out;

    // 1024 blocks x 64 threads = 1024 independent waves (1/SIMD), 4 batches each
    lstm_wave<<<dim3(1024), dim3(64), 0, stream>>>(
        x, W_ih, W_hh, b_ih, b_hh, W_dense, b_dense, out);
}